// Round 15
// baseline (406.433 us; speedup 1.0000x reference)
//
#include <hip/hip_runtime.h>

// ---------------------------------------------------------------------------
// DeformableTransformerEncoderLayer on MI355X (gfx950)
// B=4, LQ=13294, DM=256, DFFN=1024, NL=4, NH=8, NP=4, HD=32
// M = 53176 rows, padded tiles to Mp = 53248.
// Round 15: FFN fused into ONE kernel (h never hits HBM: 218 MB saved).
//   ffn_fused: per 64-row band, 8 chunks of DFFN=128:
//     phase1: h_chunk = relu(x @ W1T[chunk] + b1)  (W1 dbuf gload; x from L2)
//     bounce h_chunk through XOR-swizzled LDS
//     phase2: z_acc += h_chunk @ W2T[:,chunk]      (W2 dbuf gload)
//   then fused LN2 epilogue -> d_out.
// Pipeline (6 dispatches):
//   prep_all; gemm12 (G1+G2); sample; G4LN; ffn_fused
// ---------------------------------------------------------------------------

#define LQn   13294
#define MREAL 53176
#define MP    53248

typedef __attribute__((ext_vector_type(8))) short short8;
typedef __attribute__((ext_vector_type(4))) short short4v;
typedef __attribute__((ext_vector_type(4))) float f32x4;
typedef __attribute__((ext_vector_type(2))) float f32x2;

__device__ __forceinline__ short f2bf(float f) {
    unsigned u = __float_as_uint(f);
    unsigned r = (u + 0x7FFFu + ((u >> 16) & 1u)) >> 16;  // RNE
    return (short)r;
}
__device__ __forceinline__ float bf2f(short b) {
    return __uint_as_float(((unsigned)(unsigned short)b) << 16);
}
__device__ __forceinline__ f32x2 bf2x2(unsigned r) {
    f32x2 o;
    o.x = __uint_as_float(r << 16);
    o.y = __uint_as_float(r & 0xffff0000u);
    return o;
}

#define GLOAD16(gp, lp)                                                        \
    __builtin_amdgcn_global_load_lds(                                          \
        (const __attribute__((address_space(1))) void*)(gp),                   \
        (__attribute__((address_space(3))) void*)(lp), 16, 0, 0)

// ---------------------------------------------------------------------------
// Weight prep + bias concat + q_bf / src_bf, all in ONE dispatch.
// ---------------------------------------------------------------------------
__global__ __launch_bounds__(256) void prep_all(
    const float* __restrict__ Wv, const float* __restrict__ Ws,
    const float* __restrict__ Wa, const float* __restrict__ Wo,
    const float* __restrict__ W1, const float* __restrict__ W2,
    const float* __restrict__ bs, const float* __restrict__ ba,
    const float* __restrict__ src, const float* __restrict__ pos,
    short* __restrict__ WvT, short* __restrict__ WsaT,
    short* __restrict__ WoT, short* __restrict__ W1T,
    short* __restrict__ W2T, float* __restrict__ bsa,
    short* __restrict__ q_bf, short* __restrict__ src_bf) {
    const int bid = blockIdx.x, tid = threadIdx.x;
    if (bid >= 2945) {
        const int i = (bid - 2945) * 256 + tid;
        if (i < MREAL * 32) {
            const float4 a0 = ((const float4*)src)[i * 2];
            const float4 a1 = ((const float4*)src)[i * 2 + 1];
            const float4 b0 = ((const float4*)pos)[i * 2];
            const float4 b1 = ((const float4*)pos)[i * 2 + 1];
            short8 o, o2;
            o[0] = f2bf(a0.x + b0.x); o[1] = f2bf(a0.y + b0.y);
            o[2] = f2bf(a0.z + b0.z); o[3] = f2bf(a0.w + b0.w);
            o[4] = f2bf(a1.x + b1.x); o[5] = f2bf(a1.y + b1.y);
            o[6] = f2bf(a1.z + b1.z); o[7] = f2bf(a1.w + b1.w);
            o2[0] = f2bf(a0.x); o2[1] = f2bf(a0.y);
            o2[2] = f2bf(a0.z); o2[3] = f2bf(a0.w);
            o2[4] = f2bf(a1.x); o2[5] = f2bf(a1.y);
            o2[6] = f2bf(a1.z); o2[7] = f2bf(a1.w);
            ((short8*)q_bf)[i] = o;
            ((short8*)src_bf)[i] = o2;
        }
        return;
    }
    const float* W; short* WT; int K, N, base;
    if (bid < 256)       { W = Wv; WT = WvT;              K = 256;  N = 256;  base = 0; }
    else if (bid < 512)  { W = Ws; WT = WsaT;             K = 256;  N = 256;  base = 256; }
    else if (bid < 640)  { W = Wa; WT = WsaT + 256 * 256; K = 256;  N = 128;  base = 512; }
    else if (bid < 896)  { W = Wo; WT = WoT;              K = 256;  N = 256;  base = 640; }
    else if (bid < 1920) { W = W1; WT = W1T;              K = 256;  N = 1024; base = 896; }
    else if (bid < 2944) { W = W2; WT = W2T;              K = 1024; N = 256;  base = 1920; }
    else {
        if (tid < 256) bsa[tid] = bs[tid];
        else if (tid < 384) bsa[tid] = ba[tid - 256];
        return;
    }
    const int i = (bid - base) * 256 + tid;
    const int n = i / K, k = i - n * K;
    WT[i] = f2bf(W[(size_t)k * N + n]);
}

// ---------------------------------------------------------------------------
// bf16 MFMA GEMM body. 128x128 tile, BK=32, 4 waves, 16x16x32 MFMA.
// Dbuf global_load_lds staging; NT-swizzled block id d.
// EPI: 1 = bf16+bias; 5 = bf16+bias head-major scatter
// ---------------------------------------------------------------------------
template <int EPI, int NT>
__device__ __forceinline__ void gemm_body(short* lA, short* lB,
                                          const short* __restrict__ Ab,
                                          const short* __restrict__ BT,
                                          const float* __restrict__ bias,
                                          void* C, int d,
                                          int M, int K, int N,
                                          int ldb, int ldc) {
    const int c = d & 7, j = d >> 3;
    const int jg = j / NT;
    const int m0 = (c + 8 * jg) * 128;
    const int n0 = (j - jg * NT) * 128;
    const int t = threadIdx.x;
    const int wid = t >> 6, lane = t & 63;
    const int wr = wid >> 1, wc = wid & 1;
    const int quad = lane >> 4, l16 = lane & 15;

    f32x4 acc[4][4];
#pragma unroll
    for (int i = 0; i < 4; ++i)
#pragma unroll
        for (int jj = 0; jj < 4; ++jj) acc[i][jj] = (f32x4){0.f, 0.f, 0.f, 0.f};

    const int grow = wid * 32 + (lane >> 2);
    const int gcol = (lane & 3) * 8;
    auto stage = [&](int buf, int k0) {
        GLOAD16(Ab + (size_t)(m0 + grow) * K + k0 + gcol,
                &lA[buf * 4096 + (wid * 32) * 32]);
        GLOAD16(Ab + (size_t)(m0 + grow + 16) * K + k0 + gcol,
                &lA[buf * 4096 + (wid * 32 + 16) * 32]);
        GLOAD16(BT + (size_t)(n0 + grow) * ldb + k0 + gcol,
                &lB[buf * 4096 + (wid * 32) * 32]);
        GLOAD16(BT + (size_t)(n0 + grow + 16) * ldb + k0 + gcol,
                &lB[buf * 4096 + (wid * 32 + 16) * 32]);
    };
    stage(0, 0);
    __syncthreads();
    int cur = 0;
    for (int k0 = 0; k0 < K; k0 += 32) {
        if (k0 + 32 < K) stage(cur ^ 1, k0 + 32);
        short8 af[4], bfr[4];
#pragma unroll
        for (int mi = 0; mi < 4; ++mi)
            af[mi] = *(const short8*)&lA[cur * 4096 + (wr * 64 + mi * 16 + l16) * 32 + quad * 8];
#pragma unroll
        for (int ni = 0; ni < 4; ++ni)
            bfr[ni] = *(const short8*)&lB[cur * 4096 + (wc * 64 + ni * 16 + l16) * 32 + quad * 8];
#pragma unroll
        for (int mi = 0; mi < 4; ++mi)
#pragma unroll
            for (int ni = 0; ni < 4; ++ni)
                acc[mi][ni] = __builtin_amdgcn_mfma_f32_16x16x32_bf16(
                    af[mi], bfr[ni], acc[mi][ni], 0, 0, 0);
        __syncthreads();
        cur ^= 1;
    }

    // ---- LDS-bounce vectorized epilogue: 2 passes of 64 cols ----
    short* lflat = lA;  // 8192 shorts = 128 x 64
#pragma unroll
    for (int p = 0; p < 2; ++p) {
        if (wc == p) {
#pragma unroll
            for (int ni = 0; ni < 4; ++ni) {
                const int lc = ni * 16 + l16;
                const float bia = bias[n0 + p * 64 + lc];
#pragma unroll
                for (int mi = 0; mi < 4; ++mi)
#pragma unroll
                    for (int r = 0; r < 4; ++r) {
                        const int lr = wr * 64 + mi * 16 + quad * 4 + r;
                        float v = acc[mi][ni][r] + bia;
                        lflat[lr * 64 + (lc ^ ((lr & 7) << 3))] = f2bf(v);
                    }
            }
        }
        __syncthreads();
#pragma unroll
        for (int i = 0; i < 4; ++i) {
            const int chunk = i * 256 + t;
            const int row = chunk >> 3;
            const int c8 = (chunk & 7) * 8;
            const int gr = m0 + row;
            if (gr < M) {
                const short8 v8 =
                    *(const short8*)&lflat[row * 64 + (c8 ^ ((row & 7) << 3))];
                const int gcl = n0 + p * 64 + c8;
                if (EPI == 5) {
                    const int b = gr / LQn, s = gr - b * LQn;
                    const int hh = gcl >> 5, dd = gcl & 31;
                    *(short8*)&((short*)C)[(((size_t)b * 8 + hh) * LQn + s) * 32 + dd] = v8;
                } else {
                    *(short8*)&((short*)C)[(size_t)gr * ldc + gcl] = v8;
                }
            }
        }
        __syncthreads();
    }
}

// G1 (blocks [0,832)) and G2 (blocks [832,2080)) in one dispatch.
__global__ __launch_bounds__(256) void gemm12(const short* __restrict__ src_bf,
                                              const short* __restrict__ WvT,
                                              const float* __restrict__ bv,
                                              short* __restrict__ value_h,
                                              const short* __restrict__ q_bf,
                                              const short* __restrict__ WsaT,
                                              const float* __restrict__ bsa,
                                              short* __restrict__ offaw) {
    __shared__ short sA[2 * 128 * 32];
    __shared__ short sB[2 * 128 * 32];
    if (blockIdx.x < 832)
        gemm_body<5, 2>(sA, sB, src_bf, WvT, bv, value_h, blockIdx.x,
                        MREAL, 256, 256, 256, 256);
    else
        gemm_body<1, 3>(sA, sB, q_bf, WsaT, bsa, offaw, blockIdx.x - 832,
                        MREAL, 256, 384, 256, 384);
}

// ---------------------------------------------------------------------------
// 512-thread 64x256-tile GEMM with fused row-LayerNorm epilogue (G4+LN1).
// Output = bf16 (bounce). resbf: residual dtype (1 = bf16, 0 = fp32).
// ---------------------------------------------------------------------------
__global__ __launch_bounds__(512) void gemm_ln0(const short* __restrict__ Ab,
                                                const short* __restrict__ BT,
                                                const float* __restrict__ bias,
                                                const void* __restrict__ resid,
                                                void* __restrict__ out,
                                                const float* __restrict__ g,
                                                const float* __restrict__ be,
                                                int M, int K, int resbf) {
    const int t = threadIdx.x;
    const int m0 = blockIdx.x * 64;
    const int wid = t >> 6, lane = t & 63;
    const int wr = wid >> 2, wc = wid & 3;
    const int quad = lane >> 4, l16 = lane & 15;

    __shared__ short lA[2][64 * 32];
    __shared__ short lB[2][256 * 32];
    __shared__ float2 part[64][4];
    __shared__ float2 stats[64];

    f32x4 acc[2][4];
#pragma unroll
    for (int i = 0; i < 2; ++i)
#pragma unroll
        for (int j = 0; j < 4; ++j) acc[i][j] = (f32x4){0.f, 0.f, 0.f, 0.f};

    const int gb_row = wid * 32 + (lane >> 2);
    const int gcol8 = (lane & 3) * 8;
    auto stage = [&](int buf, int k0) {
        if (wid < 4)
            GLOAD16(Ab + (size_t)(m0 + wid * 16 + (lane >> 2)) * K + k0 + gcol8,
                    &lA[buf][(wid * 16) * 32]);
        GLOAD16(BT + (size_t)gb_row * K + k0 + gcol8,
                &lB[buf][(wid * 32) * 32]);
        GLOAD16(BT + (size_t)(gb_row + 16) * K + k0 + gcol8,
                &lB[buf][(wid * 32 + 16) * 32]);
    };
    stage(0, 0);
    __syncthreads();
    int cur = 0;
    for (int k0 = 0; k0 < K; k0 += 32) {
        if (k0 + 32 < K) stage(cur ^ 1, k0 + 32);
        short8 af[2], bfr[4];
#pragma unroll
        for (int mi = 0; mi < 2; ++mi)
            af[mi] = *(const short8*)&lA[cur][(wr * 32 + mi * 16 + l16) * 32 + quad * 8];
#pragma unroll
        for (int ni = 0; ni < 4; ++ni)
            bfr[ni] = *(const short8*)&lB[cur][(wc * 64 + ni * 16 + l16) * 32 + quad * 8];
#pragma unroll
        for (int mi = 0; mi < 2; ++mi)
#pragma unroll
            for (int ni = 0; ni < 4; ++ni)
                acc[mi][ni] = __builtin_amdgcn_mfma_f32_16x16x32_bf16(
                    af[mi], bfr[ni], acc[mi][ni], 0, 0, 0);
        __syncthreads();
        cur ^= 1;
    }

    float biasv[4], gv[4], bev[4];
    int gcs[4];
#pragma unroll
    for (int ni = 0; ni < 4; ++ni) {
        gcs[ni] = wc * 64 + ni * 16 + l16;
        biasv[ni] = bias[gcs[ni]];
        gv[ni] = g[gcs[ni]];
        bev[ni] = be[gcs[ni]];
    }
#pragma unroll
    for (int mi = 0; mi < 2; ++mi) {
#pragma unroll
        for (int r = 0; r < 4; ++r) {
            const int lr = wr * 32 + mi * 16 + quad * 4 + r;
            const int gr = m0 + lr;
            const bool ok = (gr < M);
            float s1 = 0.f, s2 = 0.f;
#pragma unroll
            for (int ni = 0; ni < 4; ++ni) {
                float v = acc[mi][ni][r] + biasv[ni];
                if (ok) {
                    if (resbf)
                        v += bf2f(((const short*)resid)[(size_t)gr * 256 + gcs[ni]]);
                    else
                        v += ((const float*)resid)[(size_t)gr * 256 + gcs[ni]];
                }
                acc[mi][ni][r] = v;
                s1 += v;
                s2 += v * v;
            }
#pragma unroll
            for (int o = 1; o < 16; o <<= 1) {
                s1 += __shfl_xor(s1, o);
                s2 += __shfl_xor(s2, o);
            }
            if (l16 == 0) part[lr][wc] = make_float2(s1, s2);
        }
    }
    __syncthreads();
    if (t < 64) {
        float s1 = 0.f, s2 = 0.f;
#pragma unroll
        for (int w = 0; w < 4; ++w) {
            const float2 p = part[t][w];
            s1 += p.x;
            s2 += p.y;
        }
        const float mean = s1 * (1.0f / 256.0f);
        const float var = s2 * (1.0f / 256.0f) - mean * mean;
        stats[t] = make_float2(mean, rsqrtf(var + 1e-5f));
    }
    __syncthreads();

    short* lflat = (short*)lA;  // 4096 shorts = 64 x 64
#pragma unroll
    for (int p = 0; p < 4; ++p) {
        if (wc == p) {
#pragma unroll
            for (int mi = 0; mi < 2; ++mi)
#pragma unroll
                for (int r = 0; r < 4; ++r) {
                    const int lr = wr * 32 + mi * 16 + quad * 4 + r;
                    const float2 st = stats[lr];
#pragma unroll
                    for (int ni = 0; ni < 4; ++ni) {
                        const int lc = ni * 16 + l16;
                        const float v =
                            (acc[mi][ni][r] - st.x) * st.y * gv[ni] + bev[ni];
                        lflat[lr * 64 + (lc ^ ((lr & 7) << 3))] = f2bf(v);
                    }
                }
        }
        __syncthreads();
        {
            const int row = t >> 3;
            const int c8 = (t & 7) * 8;
            const int gr = m0 + row;
            if (gr < M) {
                const short8 v8 =
                    *(const short8*)&lflat[row * 64 + (c8 ^ ((row & 7) << 3))];
                *(short8*)&((short*)out)[(size_t)gr * 256 + p * 64 + c8] = v8;
            }
        }
        __syncthreads();
    }
}

// ---------------------------------------------------------------------------
// Fused FFN: d_out = LN(x + relu(x@W1T+b1)@W2T + b2), h never leaves LDS.
// 64-row band per block, 512 threads, 8 chunks of DFFN=128.
// LDS ~67 KB -> 2 blocks/CU. x fragments read from global (L2-resident).
// ---------------------------------------------------------------------------
__global__ __launch_bounds__(512) void ffn_fused(const short* __restrict__ x,
                                                 const short* __restrict__ W1T,
                                                 const float* __restrict__ b1,
                                                 const short* __restrict__ W2T,
                                                 const float* __restrict__ b2,
                                                 float* __restrict__ z,
                                                 const float* __restrict__ g,
                                                 const float* __restrict__ be,
                                                 int M) {
    const int t = threadIdx.x;
    const int m0 = blockIdx.x * 64;
    const int wid = t >> 6, lane = t & 63;
    const int wr = wid >> 2, wc = wid & 3;   // phase1: wc/4 is col-pair idx
    const int quad = lane >> 4, l16 = lane & 15;
    const int s_row = lane >> 2, s_col8 = (lane & 3) * 8;

    __shared__ short lW1[2][128 * 32];
    __shared__ short lW2[2][256 * 32];
    __shared__ short lH[64 * 128];
    __shared__ float2 part[64][4];
    __shared__ float2 stats[64];

    f32x4 acc2[2][4];
#pragma unroll
    for (int i = 0; i < 2; ++i)
#pragma unroll
        for (int j = 0; j < 4; ++j) acc2[i][j] = (f32x4){0.f, 0.f, 0.f, 0.f};

    // x fragment rows (clamped to M-1; pad rows produce garbage, stores guarded)
    int xrow[2];
#pragma unroll
    for (int mi = 0; mi < 2; ++mi)
        xrow[mi] = min(m0 + wr * 32 + mi * 16 + l16, M - 1);

    for (int nc = 0; nc < 8; ++nc) {
        // ---- phase 1: h_chunk(64x128) = relu(x @ W1T[nc*128..+128] + b1) ----
        f32x4 acc1[2][2];
#pragma unroll
        for (int i = 0; i < 2; ++i)
#pragma unroll
            for (int j = 0; j < 2; ++j) acc1[i][j] = (f32x4){0.f, 0.f, 0.f, 0.f};

        auto stage1 = [&](int buf, int kk) {
            GLOAD16(W1T + (size_t)(nc * 128 + wid * 16 + s_row) * 256 + kk * 32 + s_col8,
                    &lW1[buf][(wid * 16) * 32]);
        };
        stage1(0, 0);
        __syncthreads();
        int cur = 0;
#pragma unroll
        for (int kk = 0; kk < 8; ++kk) {
            if (kk < 7) stage1(cur ^ 1, kk + 1);
            short8 ax[2];
#pragma unroll
            for (int mi = 0; mi < 2; ++mi)
                ax[mi] = *(const short8*)&x[(size_t)xrow[mi] * 256 + kk * 32 + quad * 8];
            short8 bw[2];
#pragma unroll
            for (int ni = 0; ni < 2; ++ni)
                bw[ni] = *(const short8*)&lW1[cur][((wc & 3) * 32 + ni * 16 + l16) * 32 + quad * 8];
#pragma unroll
            for (int mi = 0; mi < 2; ++mi)
#pragma unroll
                for (int ni = 0; ni < 2; ++ni)
                    acc1[mi][ni] = __builtin_amdgcn_mfma_f32_16x16x32_bf16(
                        ax[mi], bw[ni], acc1[mi][ni], 0, 0, 0);
            __syncthreads();
            cur ^= 1;
        }
        // ---- write h_chunk to lH (relu+bias, bf16, XOR-swizzled) ----
#pragma unroll
        for (int mi = 0; mi < 2; ++mi)
#pragma unroll
            for (int ni = 0; ni < 2; ++ni) {
                const int col = wc * 32 + ni * 16 + l16;
                const float bia = b1[nc * 128 + col];
#pragma unroll
                for (int r = 0; r < 4; ++r) {
                    const int row = wr * 32 + mi * 16 + quad * 4 + r;
                    const float v = fmaxf(acc1[mi][ni][r] + bia, 0.f);
                    lH[row * 128 + ((((col >> 3) ^ (row & 7)) << 3) | (col & 7))] =
                        f2bf(v);
                }
            }
        __syncthreads();
        // ---- phase 2: acc2 += h_chunk @ W2T[:, nc*128..+128] ----
        auto stage2 = [&](int buf, int kk) {
            GLOAD16(W2T + (size_t)(wid * 32 + s_row) * 1024 + nc * 128 + kk * 32 + s_col8,
                    &lW2[buf][(wid * 32) * 32]);
            GLOAD16(W2T + (size_t)(wid * 32 + 16 + s_row) * 1024 + nc * 128 + kk * 32 + s_col8,
                    &lW2[buf][(wid * 32 + 16) * 32]);
        };
        stage2(0, 0);
        __syncthreads();
        cur = 0;
#pragma unroll
        for (int kk = 0; kk < 4; ++kk) {
            if (kk < 3) stage2(cur ^ 1, kk + 1);
            short8 ah[2];
#pragma unroll
            for (int mi = 0; mi < 2; ++mi) {
                const int row = wr * 32 + mi * 16 + l16;
                ah[mi] = *(const short8*)&lH[row * 128 +
                                             (((kk * 4 + quad) ^ (row & 7)) << 3)];
            }
            short8 bw2[4];
#pragma unroll
            for (int ni = 0; ni < 4; ++ni)
                bw2[ni] = *(const short8*)&lW2[cur][(wc * 64 + ni * 16 + l16) * 32 + quad * 8];
#pragma unroll
            for (int mi = 0; mi < 2; ++mi)
#pragma unroll
                for (int ni = 0; ni < 4; ++ni)
                    acc2[mi][ni] = __builtin_amdgcn_mfma_f32_16x16x32_bf16(
                        ah[mi], bw2[ni], acc2[mi][ni], 0, 0, 0);
            __syncthreads();
            cur ^= 1;
        }
    }

    // ---- LN2 epilogue: z = LN(acc2 + b2 + x) -> fp32 d_out ----
    float biasv[4], gv[4], bev[4];
    int gcs[4];
#pragma unroll
    for (int ni = 0; ni < 4; ++ni) {
        gcs[ni] = wc * 64 + ni * 16 + l16;
        biasv[ni] = b2[gcs[ni]];
        gv[ni] = g[gcs[ni]];
        bev[ni] = be[gcs[ni]];
    }
#pragma unroll
    for (int mi = 0; mi < 2; ++mi) {
#pragma unroll
        for (int r = 0; r < 4; ++r) {
            const int lr = wr * 32 + mi * 16 + quad * 4 + r;
            const int gr = m0 + lr;
            const bool ok = (gr < M);
            float s1 = 0.f, s2 = 0.f;
#pragma unroll
            for (int ni = 0; ni < 4; ++ni) {
                float v = acc2[mi][ni][r] + biasv[ni];
                if (ok) v += bf2f(x[(size_t)gr * 256 + gcs[ni]]);
                acc2[mi][ni][r] = v;
                s1 += v;
                s2 += v * v;
            }
#pragma unroll
            for (int o = 1; o < 16; o <<= 1) {
                s1 += __shfl_xor(s1, o);
                s2 += __shfl_xor(s2, o);
            }
            if (l16 == 0) part[lr][wc] = make_float2(s1, s2);
        }
    }
    __syncthreads();
    if (t < 64) {
        float s1 = 0.f, s2 = 0.f;
#pragma unroll
        for (int w = 0; w < 4; ++w) {
            const float2 p = part[t][w];
            s1 += p.x;
            s2 += p.y;
        }
        const float mean = s1 * (1.0f / 256.0f);
        const float var = s2 * (1.0f / 256.0f) - mean * mean;
        stats[t] = make_float2(mean, rsqrtf(var + 1e-5f));
    }
    __syncthreads();
#pragma unroll
    for (int mi = 0; mi < 2; ++mi) {
#pragma unroll
        for (int r = 0; r < 4; ++r) {
            const int lr = wr * 32 + mi * 16 + quad * 4 + r;
            const int gr = m0 + lr;
            if (gr < M) {
                const float2 st = stats[lr];
#pragma unroll
                for (int ni = 0; ni < 4; ++ni) {
                    const float v =
                        (acc2[mi][ni][r] - st.x) * st.y * gv[ni] + bev[ni];
                    z[(size_t)gr * 256 + gcs[ni]] = v;
                }
            }
        }
    }
}

// ---------------------------------------------------------------------------
// MS deformable sampling, head-major bf16 value [B][NH][LQ][HD].
// 16 threads per (row, head); f32x2 packed accumulate; shfl {4,8} reduce.
// ---------------------------------------------------------------------------
__global__ __launch_bounds__(256) void sample_k(const short* __restrict__ value,
                                                const short* __restrict__ offaw,
                                                const float* __restrict__ refp,
                                                short* __restrict__ attn,
                                                int nwg) {
    int wg = blockIdx.x;
    {
        const int q = nwg >> 3, r = nwg & 7;
        const int xcd = wg & 7, idx = wg >> 3;
        wg = (xcd < r ? xcd * (q + 1) : r * (q + 1) + (xcd - r) * q) + idx;
    }
    const int tid = threadIdx.x;
    const int grp = wg * 16 + (tid >> 4);
    const int s16 = tid & 15;
    const int l = s16 >> 2, sub = s16 & 3;
    const int row = grp >> 3, h = grp & 7;
    const int b = row / LQn;
    const int L = (l == 0) ? 100 : (l == 1) ? 50 : (l == 2) ? 25 : 13;
    const int O = (l == 0) ? 0 : (l == 1) ? 10000 : (l == 2) ? 12500 : 13125;
    const float Lf = (float)L;

    const short* op = offaw + (size_t)row * 384 + h * 32;
    const short* ap = offaw + (size_t)row * 384 + 256 + h * 16;

    const short4v alog = *(const short4v*)(ap + l * 4);
    float lg[4];
#pragma unroll
    for (int j = 0; j < 4; ++j) lg[j] = bf2f(alog[j]);
    float m = fmaxf(fmaxf(lg[0], lg[1]), fmaxf(lg[2], lg[3]));
    m = fmaxf(m, __shfl_xor(m, 4));
    m = fmaxf(m, __shfl_xor(m, 8));
    float s = 0.f;
#pragma unroll
    for (int j = 0; j < 4; ++j) { lg[j] = __expf(lg[j] - m); s += lg[j]; }
    s += __shfl_xor(s, 4);
    s += __shfl_xor(s, 8);
    const float inv = 1.f / s;

    const float2 rxy = *(const float2*)(refp + (size_t)row * 8 + l * 2);
    const short8 ov = *(const short8*)(op + l * 8);
    const short* vlev = value + ((size_t)(b * 8 + h) * LQn + O) * 32 + sub * 8;

    f32x2 acc2[4];
#pragma unroll
    for (int j = 0; j < 4; ++j) acc2[j] = (f32x2){0.f, 0.f};

#pragma unroll 2
    for (int p = 0; p < 4; ++p) {
        const float x = fmaf(rxy.x, Lf, bf2f(ov[p * 2 + 0]) - 0.5f);
        const float y = fmaf(rxy.y, Lf, bf2f(ov[p * 2 + 1]) - 0.5f);
        const float xf = floorf(x), yf = floorf(y);
        const int ix = (int)xf, iy = (int)yf;
        const float fx = x - xf, fy = y - yf;
        const float aw = lg[p] * inv;
        const float vx0 = ((unsigned)ix < (unsigned)L) ? 1.f : 0.f;
        const float vx1 = ((unsigned)(ix + 1) < (unsigned)L) ? 1.f : 0.f;
        const float vy0 = ((unsigned)iy < (unsigned)L) ? 1.f : 0.f;
        const float vy1 = ((unsigned)(iy + 1) < (unsigned)L) ? 1.f : 0.f;
        const float gx0 = (1.f - fx) * aw, gx1 = fx * aw;
        const float w00 = gx0 * (1.f - fy) * vx0 * vy0;
        const float w10 = gx1 * (1.f - fy) * vx1 * vy0;
        const float w01 = gx0 * fy * vx0 * vy1;
        const float w11 = gx1 * fy * vx1 * vy1;
        const int ix0 = min(max(ix, 0), L - 1);
        const int ix1 = min(max(ix + 1, 0), L - 1);
        const int iy0 = min(max(iy, 0), L - 1);
        const int iy1 = min(max(iy + 1, 0), L - 1);
        const int ro0 = iy0 * L, ro1 = iy1 * L;
        const uint4 c00 = *(const uint4*)(vlev + ((ro0 + ix0) << 5));
        const uint4 c10 = *(const uint4*)(vlev + ((ro0 + ix1) << 5));
        const uint4 c01 = *(const uint4*)(vlev + ((ro1 + ix0) << 5));
        const uint4 c11 = *(const uint4*)(vlev + ((ro1 + ix1) << 5));
        const unsigned* p00 = (const unsigned*)&c00;
        const unsigned* p10 = (const unsigned*)&c10;
        const unsigned* p01 = (const unsigned*)&c01;
        const unsigned* p11 = (const unsigned*)&c11;
#pragma unroll
        for (int j = 0; j < 4; ++j)
            acc2[j] += w00 * bf2x2(p00[j]) + w10 * bf2x2(p10[j]) +
                       w01 * bf2x2(p01[j]) + w11 * bf2x2(p11[j]);
    }

    float acc[8];
#pragma unroll
    for (int j = 0; j < 4; ++j) {
        acc[j * 2] = acc2[j].x;
        acc[j * 2 + 1] = acc2[j].y;
    }
#pragma unroll
    for (int j = 0; j < 8; ++j) {
        acc[j] += __shfl_xor(acc[j], 4);
        acc[j] += __shfl_xor(acc[j], 8);
    }

    if (l == 0) {
        short8 o;
#pragma unroll
        for (int j = 0; j < 8; ++j) o[j] = f2bf(acc[j]);
        *(short8*)(attn + (size_t)row * 256 + h * 32 + sub * 8) = o;
    }
}

// ---------------------------------------------------------------------------
extern "C" void kernel_launch(void* const* d_in, const int* in_sizes, int n_in,
                              void* d_out, int out_size, void* d_ws, size_t ws_size,
                              hipStream_t stream) {
    (void)in_sizes; (void)n_in; (void)out_size;
    const float* src  = (const float*)d_in[0];
    const float* pos  = (const float*)d_in[1];
    const float* refp = (const float*)d_in[2];
    const float* Wv = (const float*)d_in[5];
    const float* bv = (const float*)d_in[6];
    const float* Ws = (const float*)d_in[7];
    const float* bs = (const float*)d_in[8];
    const float* Wa = (const float*)d_in[9];
    const float* ba = (const float*)d_in[10];
    const float* Wo = (const float*)d_in[11];
    const float* bo = (const float*)d_in[12];
    const float* W1 = (const float*)d_in[13];
    const float* b1 = (const float*)d_in[14];
    const float* W2 = (const float*)d_in[15];
    const float* b2 = (const float*)d_in[16];
    const float* g1 = (const float*)d_in[17];
    const float* be1 = (const float*)d_in[18];
    const float* g2 = (const float*)d_in[19];
    const float* be2 = (const float*)d_in[20];

    char* ws = (char*)d_ws;
    size_t off = 0;
    auto take = [&](size_t bytes) {
        char* p = ws + off;
        off += (bytes + 255) & ~(size_t)255;
        return p;
    };
    short* WvT  = (short*)take(256 * 256 * 2);
    short* WsaT = (short*)take(384 * 256 * 2);
    short* WoT  = (short*)take(256 * 256 * 2);
    short* W1T  = (short*)take(1024 * 256 * 2);
    short* W2T  = (short*)take(256 * 1024 * 2);
    float* bsa  = (float*)take(384 * 4);

    const size_t SZ_VH = (size_t)MP * 256 * 2;   // 27.3 MB
    const size_t SZ_OF = (size_t)MP * 384 * 2;   // 40.9 MB

    short* value_h = (short*)take(SZ_VH);  // later x_bf
    short* offaw   = (short*)take(SZ_OF);
    short* attn_bf = (short*)take(SZ_VH);  // q_bf then attn

    const size_t rem = (off <= ws_size) ? ws_size - off : 0;
    short* src_bf;
    int resbf_g4;
    if (rem >= SZ_VH + 256) {
        src_bf = (short*)take(SZ_VH);      // persistent; G4 resid bf16
        resbf_g4 = 1;
    } else {
        src_bf = offaw;                    // transient; G4 resid fp32
        resbf_g4 = 0;
    }

    short* q_bf = attn_bf;
    short* x_bf = value_h;
    float* z    = (float*)d_out;

    prep_all<<<9593, 256, 0, stream>>>(Wv, Ws, Wa, Wo, W1, W2, bs, ba, src, pos,
                                       WvT, WsaT, WoT, W1T, W2T, bsa, q_bf,
                                       src_bf);
    // G1 + G2 in one dispatch
    gemm12<<<2080, 256, 0, stream>>>(src_bf, WvT, bv, value_h,
                                     q_bf, WsaT, bsa, offaw);
    // Deformable sampling
    {
        const int nwg = (MREAL * 8) / 16;  // 26588 blocks
        sample_k<<<nwg, 256, 0, stream>>>(value_h, offaw, refp, attn_bf, nwg);
    }
    // G4 + LN1 fused: x_bf = LN(resid + attn @ WoT + bo)
    gemm_ln0<<<MP / 64, 512, 0, stream>>>(attn_bf, WoT, bo,
                                          resbf_g4 ? (const void*)src_bf
                                                   : (const void*)src,
                                          x_bf, g1, be1, MREAL, 256, resbf_g4);
    // Fused FFN + LN2 -> d_out
    ffn_fused<<<MP / 64, 512, 0, stream>>>(x_bf, W1T, b1, W2T, b2, z, g2, be2,
                                           MREAL);
}

// Round 16
// 363.463 us; speedup vs baseline: 1.1182x; 1.1182x over previous
//
#include <hip/hip_runtime.h>

// ---------------------------------------------------------------------------
// DeformableTransformerEncoderLayer on MI355X (gfx950)
// B=4, LQ=13294, DM=256, DFFN=1024, NL=4, NH=8, NP=4, HD=32
// M = 53176 rows, padded tiles to Mp = 53248.
// Round 16: REVERT round-15's fused FFN (189 µs vs 124: barrier-bound at
// 11% MfmaUtil, 8.5M bank conflicts). Back to R14 structure:
//   prep_all (LDS-tiled weight transpose now - coalesced); gemm12 (G1+G2);
//   sample; G4LN (64-row); G5; G6LN (64-row); full-M FFN when ws allows.
// ---------------------------------------------------------------------------

#define LQn   13294
#define MREAL 53176
#define MP    53248
#define MHALF 26588

typedef __attribute__((ext_vector_type(8))) short short8;
typedef __attribute__((ext_vector_type(4))) short short4v;
typedef __attribute__((ext_vector_type(4))) float f32x4;
typedef __attribute__((ext_vector_type(2))) float f32x2;

__device__ __forceinline__ short f2bf(float f) {
    unsigned u = __float_as_uint(f);
    unsigned r = (u + 0x7FFFu + ((u >> 16) & 1u)) >> 16;  // RNE
    return (short)r;
}
__device__ __forceinline__ float bf2f(short b) {
    return __uint_as_float(((unsigned)(unsigned short)b) << 16);
}
__device__ __forceinline__ f32x2 bf2x2(unsigned r) {
    f32x2 o;
    o.x = __uint_as_float(r << 16);
    o.y = __uint_as_float(r & 0xffff0000u);
    return o;
}

#define GLOAD16(gp, lp)                                                        \
    __builtin_amdgcn_global_load_lds(                                          \
        (const __attribute__((address_space(1))) void*)(gp),                   \
        (__attribute__((address_space(3))) void*)(lp), 16, 0, 0)

// ---------------------------------------------------------------------------
// Weight prep (64x64 LDS-tiled transpose, coalesced both sides) + bias concat
// + q_bf / src_bf converts, all in ONE dispatch.
// blocks [0,184): transpose tiles; 184: bias; [185, 6832): q/src convert.
// ---------------------------------------------------------------------------
__global__ __launch_bounds__(256) void prep_all(
    const float* __restrict__ Wv, const float* __restrict__ Ws,
    const float* __restrict__ Wa, const float* __restrict__ Wo,
    const float* __restrict__ W1, const float* __restrict__ W2,
    const float* __restrict__ bs, const float* __restrict__ ba,
    const float* __restrict__ src, const float* __restrict__ pos,
    short* __restrict__ WvT, short* __restrict__ WsaT,
    short* __restrict__ WoT, short* __restrict__ W1T,
    short* __restrict__ W2T, float* __restrict__ bsa,
    short* __restrict__ q_bf, short* __restrict__ src_bf) {
    const int bid = blockIdx.x, tid = threadIdx.x;
    if (bid >= 185) {
        const int i = (bid - 185) * 256 + tid;
        if (i < MREAL * 32) {
            const float4 a0 = ((const float4*)src)[i * 2];
            const float4 a1 = ((const float4*)src)[i * 2 + 1];
            const float4 b0 = ((const float4*)pos)[i * 2];
            const float4 b1 = ((const float4*)pos)[i * 2 + 1];
            short8 o, o2;
            o[0] = f2bf(a0.x + b0.x); o[1] = f2bf(a0.y + b0.y);
            o[2] = f2bf(a0.z + b0.z); o[3] = f2bf(a0.w + b0.w);
            o[4] = f2bf(a1.x + b1.x); o[5] = f2bf(a1.y + b1.y);
            o[6] = f2bf(a1.z + b1.z); o[7] = f2bf(a1.w + b1.w);
            o2[0] = f2bf(a0.x); o2[1] = f2bf(a0.y);
            o2[2] = f2bf(a0.z); o2[3] = f2bf(a0.w);
            o2[4] = f2bf(a1.x); o2[5] = f2bf(a1.y);
            o2[6] = f2bf(a1.z); o2[7] = f2bf(a1.w);
            ((short8*)q_bf)[i] = o;
            ((short8*)src_bf)[i] = o2;
        }
        return;
    }
    if (bid == 184) {
        if (tid < 256) bsa[tid] = bs[tid];
        else if (tid < 384) bsa[tid] = ba[tid - 256];
        return;
    }
    // 64x64 tiled transpose: WT[n*K+k] = bf16(W[k*N+n])
    const float* W; short* WT; int K, N, base;
    if (bid < 16)       { W = Wv; WT = WvT;              K = 256;  N = 256;  base = 0; }
    else if (bid < 32)  { W = Ws; WT = WsaT;             K = 256;  N = 256;  base = 16; }
    else if (bid < 40)  { W = Wa; WT = WsaT + 256 * 256; K = 256;  N = 128;  base = 32; }
    else if (bid < 56)  { W = Wo; WT = WoT;              K = 256;  N = 256;  base = 40; }
    else if (bid < 120) { W = W1; WT = W1T;              K = 256;  N = 1024; base = 56; }
    else                { W = W2; WT = W2T;              K = 1024; N = 256;  base = 120; }
    const int tn = N >> 6;
    const int ti = bid - base;
    const int k0 = (ti / tn) * 64, n0 = (ti - (ti / tn) * tn) * 64;
    __shared__ float tile[64][65];
    const int lr = tid >> 6, lc = tid & 63;   // 4 rows x 64 cols per pass
#pragma unroll
    for (int r = 0; r < 16; ++r)
        tile[r * 4 + lr][lc] = W[(size_t)(k0 + r * 4 + lr) * N + n0 + lc];
    __syncthreads();
#pragma unroll
    for (int r = 0; r < 16; ++r) {
        const int nn = r * 4 + lr;
        WT[(size_t)(n0 + nn) * K + k0 + lc] = f2bf(tile[lc][nn]);
    }
}

// ---------------------------------------------------------------------------
// bf16 MFMA GEMM body. 128x128 tile, BK=32, 4 waves, 16x16x32 MFMA.
// Dbuf global_load_lds staging; NT-swizzled block id d.
// EPI: 1 = bf16+bias; 2 = relu->bf16+bias; 5 = bf16+bias head-major scatter
// ---------------------------------------------------------------------------
template <int EPI, int NT>
__device__ __forceinline__ void gemm_body(short* lA, short* lB,
                                          const short* __restrict__ Ab,
                                          const short* __restrict__ BT,
                                          const float* __restrict__ bias,
                                          void* C, int d,
                                          int M, int K, int N,
                                          int ldb, int ldc) {
    const int c = d & 7, j = d >> 3;
    const int jg = j / NT;
    const int m0 = (c + 8 * jg) * 128;
    const int n0 = (j - jg * NT) * 128;
    const int t = threadIdx.x;
    const int wid = t >> 6, lane = t & 63;
    const int wr = wid >> 1, wc = wid & 1;
    const int quad = lane >> 4, l16 = lane & 15;

    f32x4 acc[4][4];
#pragma unroll
    for (int i = 0; i < 4; ++i)
#pragma unroll
        for (int jj = 0; jj < 4; ++jj) acc[i][jj] = (f32x4){0.f, 0.f, 0.f, 0.f};

    const int grow = wid * 32 + (lane >> 2);
    const int gcol = (lane & 3) * 8;
    auto stage = [&](int buf, int k0) {
        GLOAD16(Ab + (size_t)(m0 + grow) * K + k0 + gcol,
                &lA[buf * 4096 + (wid * 32) * 32]);
        GLOAD16(Ab + (size_t)(m0 + grow + 16) * K + k0 + gcol,
                &lA[buf * 4096 + (wid * 32 + 16) * 32]);
        GLOAD16(BT + (size_t)(n0 + grow) * ldb + k0 + gcol,
                &lB[buf * 4096 + (wid * 32) * 32]);
        GLOAD16(BT + (size_t)(n0 + grow + 16) * ldb + k0 + gcol,
                &lB[buf * 4096 + (wid * 32 + 16) * 32]);
    };
    stage(0, 0);
    __syncthreads();
    int cur = 0;
    for (int k0 = 0; k0 < K; k0 += 32) {
        if (k0 + 32 < K) stage(cur ^ 1, k0 + 32);
        short8 af[4], bfr[4];
#pragma unroll
        for (int mi = 0; mi < 4; ++mi)
            af[mi] = *(const short8*)&lA[cur * 4096 + (wr * 64 + mi * 16 + l16) * 32 + quad * 8];
#pragma unroll
        for (int ni = 0; ni < 4; ++ni)
            bfr[ni] = *(const short8*)&lB[cur * 4096 + (wc * 64 + ni * 16 + l16) * 32 + quad * 8];
#pragma unroll
        for (int mi = 0; mi < 4; ++mi)
#pragma unroll
            for (int ni = 0; ni < 4; ++ni)
                acc[mi][ni] = __builtin_amdgcn_mfma_f32_16x16x32_bf16(
                    af[mi], bfr[ni], acc[mi][ni], 0, 0, 0);
        __syncthreads();
        cur ^= 1;
    }

    // ---- LDS-bounce vectorized epilogue: 2 passes of 64 cols ----
    short* lflat = lA;  // 8192 shorts = 128 x 64
#pragma unroll
    for (int p = 0; p < 2; ++p) {
        if (wc == p) {
#pragma unroll
            for (int ni = 0; ni < 4; ++ni) {
                const int lc = ni * 16 + l16;
                const float bia = bias[n0 + p * 64 + lc];
#pragma unroll
                for (int mi = 0; mi < 4; ++mi)
#pragma unroll
                    for (int r = 0; r < 4; ++r) {
                        const int lr = wr * 64 + mi * 16 + quad * 4 + r;
                        float v = acc[mi][ni][r] + bia;
                        if (EPI == 2) v = fmaxf(v, 0.f);
                        lflat[lr * 64 + (lc ^ ((lr & 7) << 3))] = f2bf(v);
                    }
            }
        }
        __syncthreads();
#pragma unroll
        for (int i = 0; i < 4; ++i) {
            const int chunk = i * 256 + t;
            const int row = chunk >> 3;
            const int c8 = (chunk & 7) * 8;
            const int gr = m0 + row;
            if (gr < M) {
                const short8 v8 =
                    *(const short8*)&lflat[row * 64 + (c8 ^ ((row & 7) << 3))];
                const int gcl = n0 + p * 64 + c8;
                if (EPI == 5) {
                    const int b = gr / LQn, s = gr - b * LQn;
                    const int hh = gcl >> 5, dd = gcl & 31;
                    *(short8*)&((short*)C)[(((size_t)b * 8 + hh) * LQn + s) * 32 + dd] = v8;
                } else {
                    *(short8*)&((short*)C)[(size_t)gr * ldc + gcl] = v8;
                }
            }
        }
        __syncthreads();
    }
}

template <int EPI, int NT>
__global__ __launch_bounds__(256) void gemm_bt(const short* __restrict__ Ab,
                                               const short* __restrict__ BT,
                                               const float* __restrict__ bias,
                                               void* C, int M, int K, int N,
                                               int ldb, int ldc) {
    __shared__ short sA[2 * 128 * 32];
    __shared__ short sB[2 * 128 * 32];
    gemm_body<EPI, NT>(sA, sB, Ab, BT, bias, C, blockIdx.x, M, K, N, ldb, ldc);
}

// G1 (blocks [0,832)) and G2 (blocks [832,2080)) in one dispatch.
__global__ __launch_bounds__(256) void gemm12(const short* __restrict__ src_bf,
                                              const short* __restrict__ WvT,
                                              const float* __restrict__ bv,
                                              short* __restrict__ value_h,
                                              const short* __restrict__ q_bf,
                                              const short* __restrict__ WsaT,
                                              const float* __restrict__ bsa,
                                              short* __restrict__ offaw) {
    __shared__ short sA[2 * 128 * 32];
    __shared__ short sB[2 * 128 * 32];
    if (blockIdx.x < 832)
        gemm_body<5, 2>(sA, sB, src_bf, WvT, bv, value_h, blockIdx.x,
                        MREAL, 256, 256, 256, 256);
    else
        gemm_body<1, 3>(sA, sB, q_bf, WsaT, bsa, offaw, blockIdx.x - 832,
                        MREAL, 256, 384, 256, 384);
}

// ---------------------------------------------------------------------------
// 512-thread 64x256-tile GEMM with fused row-LayerNorm epilogue.
// 8 waves = 2 row-bands x 4 col-bands; acc[2][4]. ~43 KB LDS -> 3 blocks/CU.
// EPI 0: output = bf16 (bounce). EPI 1: output = fp32.
// resbf: residual dtype (1 = bf16, 0 = fp32). N = 256 fixed, ldc = 256.
// ---------------------------------------------------------------------------
template <int EPI>
__global__ __launch_bounds__(512) void gemm_ln(const short* __restrict__ Ab,
                                               const short* __restrict__ BT,
                                               const float* __restrict__ bias,
                                               const void* __restrict__ resid,
                                               void* __restrict__ out,
                                               const float* __restrict__ g,
                                               const float* __restrict__ be,
                                               int M, int K, int resbf) {
    const int t = threadIdx.x;
    const int m0 = blockIdx.x * 64;
    const int wid = t >> 6, lane = t & 63;
    const int wr = wid >> 2, wc = wid & 3;
    const int quad = lane >> 4, l16 = lane & 15;

    __shared__ short lA[2][64 * 32];
    __shared__ short lB[2][256 * 32];
    __shared__ float2 part[64][4];
    __shared__ float2 stats[64];

    f32x4 acc[2][4];
#pragma unroll
    for (int i = 0; i < 2; ++i)
#pragma unroll
        for (int j = 0; j < 4; ++j) acc[i][j] = (f32x4){0.f, 0.f, 0.f, 0.f};

    const int gb_row = wid * 32 + (lane >> 2);
    const int gcol8 = (lane & 3) * 8;
    auto stage = [&](int buf, int k0) {
        if (wid < 4)
            GLOAD16(Ab + (size_t)(m0 + wid * 16 + (lane >> 2)) * K + k0 + gcol8,
                    &lA[buf][(wid * 16) * 32]);
        GLOAD16(BT + (size_t)gb_row * K + k0 + gcol8,
                &lB[buf][(wid * 32) * 32]);
        GLOAD16(BT + (size_t)(gb_row + 16) * K + k0 + gcol8,
                &lB[buf][(wid * 32 + 16) * 32]);
    };
    stage(0, 0);
    __syncthreads();
    int cur = 0;
    for (int k0 = 0; k0 < K; k0 += 32) {
        if (k0 + 32 < K) stage(cur ^ 1, k0 + 32);
        short8 af[2], bfr[4];
#pragma unroll
        for (int mi = 0; mi < 2; ++mi)
            af[mi] = *(const short8*)&lA[cur][(wr * 32 + mi * 16 + l16) * 32 + quad * 8];
#pragma unroll
        for (int ni = 0; ni < 4; ++ni)
            bfr[ni] = *(const short8*)&lB[cur][(wc * 64 + ni * 16 + l16) * 32 + quad * 8];
#pragma unroll
        for (int mi = 0; mi < 2; ++mi)
#pragma unroll
            for (int ni = 0; ni < 4; ++ni)
                acc[mi][ni] = __builtin_amdgcn_mfma_f32_16x16x32_bf16(
                    af[mi], bfr[ni], acc[mi][ni], 0, 0, 0);
        __syncthreads();
        cur ^= 1;
    }

    float biasv[4], gv[4], bev[4];
    int gcs[4];
#pragma unroll
    for (int ni = 0; ni < 4; ++ni) {
        gcs[ni] = wc * 64 + ni * 16 + l16;
        biasv[ni] = bias[gcs[ni]];
        gv[ni] = g[gcs[ni]];
        bev[ni] = be[gcs[ni]];
    }
#pragma unroll
    for (int mi = 0; mi < 2; ++mi) {
#pragma unroll
        for (int r = 0; r < 4; ++r) {
            const int lr = wr * 32 + mi * 16 + quad * 4 + r;
            const int gr = m0 + lr;
            const bool ok = (gr < M);
            float s1 = 0.f, s2 = 0.f;
#pragma unroll
            for (int ni = 0; ni < 4; ++ni) {
                float v = acc[mi][ni][r] + biasv[ni];
                if (ok) {
                    if (resbf)
                        v += bf2f(((const short*)resid)[(size_t)gr * 256 + gcs[ni]]);
                    else
                        v += ((const float*)resid)[(size_t)gr * 256 + gcs[ni]];
                }
                acc[mi][ni][r] = v;
                s1 += v;
                s2 += v * v;
            }
#pragma unroll
            for (int o = 1; o < 16; o <<= 1) {
                s1 += __shfl_xor(s1, o);
                s2 += __shfl_xor(s2, o);
            }
            if (l16 == 0) part[lr][wc] = make_float2(s1, s2);
        }
    }
    __syncthreads();
    if (t < 64) {
        float s1 = 0.f, s2 = 0.f;
#pragma unroll
        for (int w = 0; w < 4; ++w) {
            const float2 p = part[t][w];
            s1 += p.x;
            s2 += p.y;
        }
        const float mean = s1 * (1.0f / 256.0f);
        const float var = s2 * (1.0f / 256.0f) - mean * mean;
        stats[t] = make_float2(mean, rsqrtf(var + 1e-5f));
    }
    __syncthreads();

    if (EPI == 0) {
        short* lflat = (short*)lA;  // 4096 shorts = 64 x 64
#pragma unroll
        for (int p = 0; p < 4; ++p) {
            if (wc == p) {
#pragma unroll
                for (int mi = 0; mi < 2; ++mi)
#pragma unroll
                    for (int r = 0; r < 4; ++r) {
                        const int lr = wr * 32 + mi * 16 + quad * 4 + r;
                        const float2 st = stats[lr];
#pragma unroll
                        for (int ni = 0; ni < 4; ++ni) {
                            const int lc = ni * 16 + l16;
                            const float v =
                                (acc[mi][ni][r] - st.x) * st.y * gv[ni] + bev[ni];
                            lflat[lr * 64 + (lc ^ ((lr & 7) << 3))] = f2bf(v);
                        }
                    }
            }
            __syncthreads();
            {
                const int row = t >> 3;
                const int c8 = (t & 7) * 8;
                const int gr = m0 + row;
                if (gr < M) {
                    const short8 v8 =
                        *(const short8*)&lflat[row * 64 + (c8 ^ ((row & 7) << 3))];
                    *(short8*)&((short*)out)[(size_t)gr * 256 + p * 64 + c8] = v8;
                }
            }
            __syncthreads();
        }
    } else {
#pragma unroll
        for (int mi = 0; mi < 2; ++mi) {
#pragma unroll
            for (int r = 0; r < 4; ++r) {
                const int lr = wr * 32 + mi * 16 + quad * 4 + r;
                const int gr = m0 + lr;
                if (gr < M) {
                    const float2 st = stats[lr];
#pragma unroll
                    for (int ni = 0; ni < 4; ++ni) {
                        const float v =
                            (acc[mi][ni][r] - st.x) * st.y * gv[ni] + bev[ni];
                        ((float*)out)[(size_t)gr * 256 + gcs[ni]] = v;
                    }
                }
            }
        }
    }
}

// ---------------------------------------------------------------------------
// MS deformable sampling, head-major bf16 value [B][NH][LQ][HD].
// 16 threads per (row, head); f32x2 packed accumulate; shfl {4,8} reduce.
// ---------------------------------------------------------------------------
__global__ __launch_bounds__(256) void sample_k(const short* __restrict__ value,
                                                const short* __restrict__ offaw,
                                                const float* __restrict__ refp,
                                                short* __restrict__ attn,
                                                int nwg) {
    int wg = blockIdx.x;
    {
        const int q = nwg >> 3, r = nwg & 7;
        const int xcd = wg & 7, idx = wg >> 3;
        wg = (xcd < r ? xcd * (q + 1) : r * (q + 1) + (xcd - r) * q) + idx;
    }
    const int tid = threadIdx.x;
    const int grp = wg * 16 + (tid >> 4);
    const int s16 = tid & 15;
    const int l = s16 >> 2, sub = s16 & 3;
    const int row = grp >> 3, h = grp & 7;
    const int b = row / LQn;
    const int L = (l == 0) ? 100 : (l == 1) ? 50 : (l == 2) ? 25 : 13;
    const int O = (l == 0) ? 0 : (l == 1) ? 10000 : (l == 2) ? 12500 : 13125;
    const float Lf = (float)L;

    const short* op = offaw + (size_t)row * 384 + h * 32;
    const short* ap = offaw + (size_t)row * 384 + 256 + h * 16;

    const short4v alog = *(const short4v*)(ap + l * 4);
    float lg[4];
#pragma unroll
    for (int j = 0; j < 4; ++j) lg[j] = bf2f(alog[j]);
    float m = fmaxf(fmaxf(lg[0], lg[1]), fmaxf(lg[2], lg[3]));
    m = fmaxf(m, __shfl_xor(m, 4));
    m = fmaxf(m, __shfl_xor(m, 8));
    float s = 0.f;
#pragma unroll
    for (int j = 0; j < 4; ++j) { lg[j] = __expf(lg[j] - m); s += lg[j]; }
    s += __shfl_xor(s, 4);
    s += __shfl_xor(s, 8);
    const float inv = 1.f / s;

    const float2 rxy = *(const float2*)(refp + (size_t)row * 8 + l * 2);
    const short8 ov = *(const short8*)(op + l * 8);
    const short* vlev = value + ((size_t)(b * 8 + h) * LQn + O) * 32 + sub * 8;

    f32x2 acc2[4];
#pragma unroll
    for (int j = 0; j < 4; ++j) acc2[j] = (f32x2){0.f, 0.f};

#pragma unroll 2
    for (int p = 0; p < 4; ++p) {
        const float x = fmaf(rxy.x, Lf, bf2f(ov[p * 2 + 0]) - 0.5f);
        const float y = fmaf(rxy.y, Lf, bf2f(ov[p * 2 + 1]) - 0.5f);
        const float xf = floorf(x), yf = floorf(y);
        const int ix = (int)xf, iy = (int)yf;
        const float fx = x - xf, fy = y - yf;
        const float aw = lg[p] * inv;
        const float vx0 = ((unsigned)ix < (unsigned)L) ? 1.f : 0.f;
        const float vx1 = ((unsigned)(ix + 1) < (unsigned)L) ? 1.f : 0.f;
        const float vy0 = ((unsigned)iy < (unsigned)L) ? 1.f : 0.f;
        const float vy1 = ((unsigned)(iy + 1) < (unsigned)L) ? 1.f : 0.f;
        const float gx0 = (1.f - fx) * aw, gx1 = fx * aw;
        const float w00 = gx0 * (1.f - fy) * vx0 * vy0;
        const float w10 = gx1 * (1.f - fy) * vx1 * vy0;
        const float w01 = gx0 * fy * vx0 * vy1;
        const float w11 = gx1 * fy * vx1 * vy1;
        const int ix0 = min(max(ix, 0), L - 1);
        const int ix1 = min(max(ix + 1, 0), L - 1);
        const int iy0 = min(max(iy, 0), L - 1);
        const int iy1 = min(max(iy + 1, 0), L - 1);
        const int ro0 = iy0 * L, ro1 = iy1 * L;
        const uint4 c00 = *(const uint4*)(vlev + ((ro0 + ix0) << 5));
        const uint4 c10 = *(const uint4*)(vlev + ((ro0 + ix1) << 5));
        const uint4 c01 = *(const uint4*)(vlev + ((ro1 + ix0) << 5));
        const uint4 c11 = *(const uint4*)(vlev + ((ro1 + ix1) << 5));
        const unsigned* p00 = (const unsigned*)&c00;
        const unsigned* p10 = (const unsigned*)&c10;
        const unsigned* p01 = (const unsigned*)&c01;
        const unsigned* p11 = (const unsigned*)&c11;
#pragma unroll
        for (int j = 0; j < 4; ++j)
            acc2[j] += w00 * bf2x2(p00[j]) + w10 * bf2x2(p10[j]) +
                       w01 * bf2x2(p01[j]) + w11 * bf2x2(p11[j]);
    }

    float acc[8];
#pragma unroll
    for (int j = 0; j < 4; ++j) {
        acc[j * 2] = acc2[j].x;
        acc[j * 2 + 1] = acc2[j].y;
    }
#pragma unroll
    for (int j = 0; j < 8; ++j) {
        acc[j] += __shfl_xor(acc[j], 4);
        acc[j] += __shfl_xor(acc[j], 8);
    }

    if (l == 0) {
        short8 o;
#pragma unroll
        for (int j = 0; j < 8; ++j) o[j] = f2bf(acc[j]);
        *(short8*)(attn + (size_t)row * 256 + h * 32 + sub * 8) = o;
    }
}

// ---------------------------------------------------------------------------
extern "C" void kernel_launch(void* const* d_in, const int* in_sizes, int n_in,
                              void* d_out, int out_size, void* d_ws, size_t ws_size,
                              hipStream_t stream) {
    (void)in_sizes; (void)n_in; (void)out_size;
    const float* src  = (const float*)d_in[0];
    const float* pos  = (const float*)d_in[1];
    const float* refp = (const float*)d_in[2];
    const float* Wv = (const float*)d_in[5];
    const float* bv = (const float*)d_in[6];
    const float* Ws = (const float*)d_in[7];
    const float* bs = (const float*)d_in[8];
    const float* Wa = (const float*)d_in[9];
    const float* ba = (const float*)d_in[10];
    const float* Wo = (const float*)d_in[11];
    const float* bo = (const float*)d_in[12];
    const float* W1 = (const float*)d_in[13];
    const float* b1 = (const float*)d_in[14];
    const float* W2 = (const float*)d_in[15];
    const float* b2 = (const float*)d_in[16];
    const float* g1 = (const float*)d_in[17];
    const float* be1 = (const float*)d_in[18];
    const float* g2 = (const float*)d_in[19];
    const float* be2 = (const float*)d_in[20];

    char* ws = (char*)d_ws;
    size_t off = 0;
    auto take = [&](size_t bytes) {
        char* p = ws + off;
        off += (bytes + 255) & ~(size_t)255;
        return p;
    };
    short* WvT  = (short*)take(256 * 256 * 2);
    short* WsaT = (short*)take(384 * 256 * 2);
    short* WoT  = (short*)take(256 * 256 * 2);
    short* W1T  = (short*)take(1024 * 256 * 2);
    short* W2T  = (short*)take(256 * 1024 * 2);
    float* bsa  = (float*)take(384 * 4);

    const size_t SZ_VH = (size_t)MP * 256 * 2;                  // 27.3 MB
    const size_t SZ_OF = (size_t)MP * 384 * 2;                  // 40.9 MB
    const size_t SZ_H  = (size_t)MP * 1024 * 2;                 // 109.1 MB
    const size_t SZ_HX = SZ_H - (SZ_OF + 2 * SZ_VH);            // 13.6 MB tail

    short* value_h = (short*)take(SZ_VH);  // later x_bf
    short* offaw   = (short*)take(SZ_OF);  // later h (start)
    short* attn_bf = (short*)take(SZ_VH);  // q_bf / attn / h span

    const size_t rem = (off <= ws_size) ? ws_size - off : 0;
    const bool cfgFull = rem >= SZ_VH + SZ_HX + 512;   // src_bf + h tail
    const bool cfgA    = !cfgFull && rem >= SZ_VH + 256;
    short* src_bf;
    int resbf_g4;
    if (cfgFull) {
        src_bf = (short*)take(SZ_VH);
        (void)take(SZ_HX);                 // h tail extension
        resbf_g4 = 1;
    } else if (cfgA) {
        src_bf = (short*)take(SZ_VH);
        resbf_g4 = 1;
    } else {
        src_bf = offaw;                    // transient
        resbf_g4 = 0;
    }

    short* q_bf = attn_bf;
    short* x_bf = value_h;
    short* h    = offaw;   // halves: spans offaw+attn; full: +src_bf+tail
    float* z    = (float*)d_out;

    prep_all<<<6832, 256, 0, stream>>>(Wv, Ws, Wa, Wo, W1, W2, bs, ba, src, pos,
                                       WvT, WsaT, WoT, W1T, W2T, bsa, q_bf,
                                       src_bf);
    // G1 + G2 in one dispatch
    gemm12<<<2080, 256, 0, stream>>>(src_bf, WvT, bv, value_h,
                                     q_bf, WsaT, bsa, offaw);
    // Deformable sampling
    {
        const int nwg = (MREAL * 8) / 16;  // 26588 blocks
        sample_k<<<nwg, 256, 0, stream>>>(value_h, offaw, refp, attn_bf, nwg);
    }
    // G4 + LN1 fused: x_bf = LN(resid + attn @ WoT + bo)   (64-row tiles)
    gemm_ln<0><<<MP / 64, 512, 0, stream>>>(attn_bf, WoT, bo,
                                            resbf_g4 ? (const void*)src_bf
                                                     : (const void*)src,
                                            x_bf, g1, be1, MREAL, 256, resbf_g4);
    if (cfgFull) {
        // FFN full-M: G5 then G6+LN2
        gemm_bt<2, 8><<<3328, 256, 0, stream>>>(
            x_bf, W1T, b1, h, MREAL, 256, 1024, 256, 1024);
        gemm_ln<1><<<MP / 64, 512, 0, stream>>>(h, W2T, b2, x_bf, z, g2, be2,
                                                MREAL, 1024, 1);
    } else {
        for (int half = 0; half < 2; ++half) {
            const size_t ro = (size_t)half * MHALF;
            gemm_bt<2, 8><<<1664, 256, 0, stream>>>(
                x_bf + ro * 256, W1T, b1, h, MHALF, 256, 1024, 256, 1024);
            gemm_ln<1><<<(MHALF + 63) / 64, 512, 0, stream>>>(
                h, W2T, b2, x_bf + ro * 256, z + ro * 256, g2, be2, MHALF, 1024,
                1);
        }
    }
}